// Round 1
// baseline (85.854 us; speedup 1.0000x reference)
//
#include <hip/hip_runtime.h>
#include <hip/hip_bf16.h>

#define BHN 32      // B*H
#define SEQ 4096
#define DIM 128
#define TROWS 64               // rows per LDS tile

typedef __bf16 bf16x8 __attribute__((ext_vector_type(8)));
typedef __bf16 bf16x4 __attribute__((ext_vector_type(4)));
typedef float  f32x4  __attribute__((ext_vector_type(4)));

__device__ __forceinline__ bf16x8 cvt8(const float* f) {
    bf16x8 r;
#pragma unroll
    for (int i = 0; i < 8; ++i) r[i] = (__bf16)f[i];
    return r;
}

// ---------------------------------------------------------------------------
// Phase 1 (low-VGPR, 8-wave): partial kv^T. C[e][d] = sum_s v[s][e]*k[s][d]
// Templated on chunk count CH. CH=32: grid = 32 heads * 32 chunks = 1024
// blocks -> 4 blocks/CU (was 2 at CH=16). Counters showed p1 latency-bound:
// MfmaUtil 2.9%, VALUBusy 2.7%, hbm 4% peak, Occupancy 35.8% -> nothing busy,
// everything waiting. Doubling resident blocks doubles the independent
// load/MFMA streams per CU. __launch_bounds__(512,8) pins VGPR<=64 so the
// 4-blocks/CU thesis can't be silently lost to regalloc drift (measured 52).
// LDS 32 KB (kt/vt [128][64] bf16) -> 5 blocks/CU capacity, grid-limited 4.
// LDS swizzle: elem (d,s) at d*64 + (((s>>3) ^ key(d))*8) + (s&7),
//   key(d) = (d&7) ^ ((d>>2)&7)   -- bijective mod 8 BOTH on consecutive d
//   (read lanes span c) and on stride-4 d (write lanes span dcol) -> <=2-way.
// Staging: per instr a wave reads 2 x 512 B full rows (perfect coalescing).
// ---------------------------------------------------------------------------
template<int CH>
__global__ __launch_bounds__(512, 8) void p1_kv(const float* __restrict__ kin,
                                                const float* __restrict__ vin,
                                                __bf16* __restrict__ ws1) {
    constexpr int SR = SEQ / CH;       // rows per block
    constexpr int NT = SR / TROWS;     // LDS tiles per block

    __shared__ __align__(16) __bf16 kt[DIM][TROWS];  // 16 KB
    __shared__ __align__(16) __bf16 vt[DIM][TROWS];  // 16 KB

    const int bh    = blockIdx.x / CH;
    const int chunk = blockIdx.x % CH;
    const int tid = threadIdx.x;

    const int dcol = tid & 31;     // d-quad index 0..31  -> d0 = dcol*4
    const int sgrp = tid >> 5;     // s-quad index 0..15  -> s0 = sgrp*4
    const int d0 = dcol * 4;
    const int s0 = sgrp * 4;

    const int w = tid >> 6;
    const int l = tid & 63;
    const int g = l >> 4;
    const int c = l & 15;

    const float* kb = kin + (size_t)bh * SEQ * DIM + (size_t)chunk * SR * DIM;
    const float* vb = vin + (size_t)bh * SEQ * DIM + (size_t)chunk * SR * DIM;

    f32x4 acc[8];
#pragma unroll
    for (int nt = 0; nt < 8; ++nt) acc[nt] = (f32x4){0.f, 0.f, 0.f, 0.f};

    for (int t = 0; t < NT; ++t) {
        // ---- load 4 rows x 16B-of-d per thread (wave: 2 full 512B rows/instr)
        const float* kp = kb + (size_t)(t * TROWS + s0) * DIM + d0;
        const float* vp = vb + (size_t)(t * TROWS + s0) * DIM + d0;
        f32x4 kr[4], vr[4];
#pragma unroll
        for (int j = 0; j < 4; ++j) {
            kr[j] = *(const f32x4*)(kp + j * DIM);
            vr[j] = *(const f32x4*)(vp + j * DIM);
        }
        // ---- transpose-pack into swizzled LDS (bf16x4 of 4 s per d-row)
#pragma unroll
        for (int jd = 0; jd < 4; ++jd) {
            const int dd  = d0 + jd;
            const int key = (dd & 7) ^ ((dd >> 2) & 7);
            const int off = (((sgrp >> 1) ^ key) * 8) + (sgrp & 1) * 4;
            bf16x4 pk, pv;
#pragma unroll
            for (int j = 0; j < 4; ++j) {
                pk[j] = (__bf16)kr[j][jd];
                pv[j] = (__bf16)vr[j][jd];
            }
            *(bf16x4*)&kt[dd][off] = pk;
            *(bf16x4*)&vt[dd][off] = pv;
        }
        __syncthreads();

        // ---- MFMA: wave w owns e-strip [w*16, w*16+16); K-dim 64 s (2 steps)
        const int e    = w * 16 + c;
        const int keyE = (e & 7) ^ ((e >> 2) & 7);
#pragma unroll
        for (int st = 0; st < 2; ++st) {
            bf16x8 af = *(const bf16x8*)&vt[e][((st * 4 + g) ^ keyE) * 8];
#pragma unroll
            for (int nt = 0; nt < 8; ++nt) {
                const int d    = nt * 16 + c;
                const int keyD = (d & 7) ^ ((d >> 2) & 7);
                bf16x8 bfr = *(const bf16x8*)&kt[d][((st * 4 + g) ^ keyD) * 8];
                acc[nt] = __builtin_amdgcn_mfma_f32_16x16x32_bf16(af, bfr, acc[nt], 0, 0, 0);
            }
        }
        __syncthreads();
    }

    // store bf16 partials, MFMA-native flat layout: f = nt*2048 + tid*4 + r
    // (each bf16x4 store instr = 512B/wave contiguous burst)
    __bf16* outp = ws1 + ((size_t)chunk * BHN + bh) * (DIM * DIM);
#pragma unroll
    for (int nt = 0; nt < 8; ++nt) {
        bf16x4 p;
#pragma unroll
        for (int r = 0; r < 4; ++r) p[r] = (__bf16)acc[nt][r];
        *(bf16x4*)(outp + nt * 2048 + tid * 4) = p;
    }
}

// ---------------------------------------------------------------------------
// Phase 1.5: reduce CH bf16 partials (fp32 accum) -> bf16 kv^T swizzled for p2:
//   element (e,d) at  e*128 + ((d>>3)^(e&15))*8 + (d&7)
// Decode of p1's flat layout  f = nt*2048 + tid*4 + r, tid = w*64+g*16+c:
//   nt=f>>11; w=(f>>8)&7; g=(f>>6)&3; c=(f>>2)&15; r=f&3
//   e = w*16 + g*4 + r ;  d = nt*16 + c
// 256 blocks * 256 threads; thread owns 8 consecutive f (16B loads/chunk).
// ---------------------------------------------------------------------------
template<int CH>
__global__ __launch_bounds__(256) void p1_reduce(const __bf16* __restrict__ ws1,
                                                 __bf16* __restrict__ ws2) {
    const int t   = blockIdx.x * 256 + threadIdx.x;  // 65536 threads
    const int bh  = t >> 11;
    const int r11 = t & 2047;

    const __bf16* base = ws1 + (size_t)bh * (DIM * DIM) + r11 * 8;
    float s[8] = {0.f, 0.f, 0.f, 0.f, 0.f, 0.f, 0.f, 0.f};
#pragma unroll
    for (int ch = 0; ch < CH; ++ch) {
        bf16x8 a = *(const bf16x8*)(base + (size_t)ch * BHN * DIM * DIM);
#pragma unroll
        for (int i = 0; i < 8; ++i) s[i] += (float)a[i];
    }

    __bf16* dst = ws2 + (size_t)bh * (DIM * DIM);
#pragma unroll
    for (int i = 0; i < 8; ++i) {
        const int f  = r11 * 8 + i;
        const int nt = f >> 11;
        const int wv = (f >> 8) & 7;
        const int gg = (f >> 6) & 3;
        const int cc = (f >> 2) & 15;
        const int r  = f & 3;
        const int e  = wv * 16 + gg * 4 + r;
        const int d  = nt * 16 + cc;
        dst[e * DIM + (((d >> 3) ^ (e & 15)) * 8) + (d & 7)] = (__bf16)s[i];
    }
}

// ---------------------------------------------------------------------------
// Phase 2 (flipped operands): out[s][e] = v[s][e] + sum_d q[s][d] * kv[d][e]
// Compute C[e][s] = mfma(A = kv_frag (M=e), B = q_frag (N=s)).
// Each lane holds 4 CONSECUTIVE e per fragment -> f32x4 epilogue.
// grid = 32 heads * 32 row-chunks = 1024 blocks, 512 threads (8 waves).
// UNCHANGED this round: VGPR=32 -> 32 waves/CU (grid-limited 4 blocks/CU);
// counters suggest it is near its streaming floor. Attack next if p1 pays off.
// ---------------------------------------------------------------------------
__global__ __launch_bounds__(512) void p2_qkv(const float* __restrict__ qin,
                                              const float* __restrict__ vin,
                                              const __bf16* __restrict__ ws2,
                                              float* __restrict__ outp) {
    __shared__ __align__(16) __bf16 kvs[DIM * DIM];

    const int bh = blockIdx.x & 31;
    const int rc = blockIdx.x >> 5;
    const int tid = threadIdx.x;

    {   // linear 16B-copy of the (already swizzled) 32 KB head slab into LDS
        const uint4* src = (const uint4*)(ws2 + (size_t)bh * DIM * DIM);
        uint4* dst = (uint4*)kvs;
#pragma unroll
        for (int j = 0; j < 4; ++j) dst[tid + j * 512] = src[tid + j * 512];
    }
    __syncthreads();

    const int w = tid >> 6;
    const int l = tid & 63;
    const int g = l >> 4;
    const int c = l & 15;
    const int s = rc * 128 + w * 16 + c;     // this lane's output row

    // hoist all 4 Q fragments: B[d][s], lane holds q[s][ks*32 + g*8 .. +8)
    const float* qrow = qin + (size_t)bh * SEQ * DIM + (size_t)s * DIM + g * 8;
    bf16x8 bq[4];
#pragma unroll
    for (int ks = 0; ks < 4; ++ks) {
        f32x4 x = *(const f32x4*)(qrow + ks * 32);
        f32x4 y = *(const f32x4*)(qrow + ks * 32 + 4);
        float tmp[8];
        tmp[0]=x[0]; tmp[1]=x[1]; tmp[2]=x[2]; tmp[3]=x[3];
        tmp[4]=y[0]; tmp[5]=y[1]; tmp[6]=y[2]; tmp[7]=y[3];
        bq[ks] = cvt8(tmp);
    }

    f32x4 acc[8];
#pragma unroll
    for (int et = 0; et < 8; ++et) acc[et] = (f32x4){0.f, 0.f, 0.f, 0.f};

#pragma unroll
    for (int ks = 0; ks < 4; ++ks) {
#pragma unroll
        for (int et = 0; et < 8; ++et) {
            const int e = et * 16 + c;                 // A's M index = lane&15
            const int slot = (ks * 4 + g) ^ c;         // unswizzle: d-slice = ks*32+g*8
            bf16x8 a = *(const bf16x8*)&kvs[e * DIM + slot * 8];
            acc[et] = __builtin_amdgcn_mfma_f32_16x16x32_bf16(a, bq[ks], acc[et], 0, 0, 0);
        }
    }

    // epilogue: lane holds out[s][et*16 + g*4 .. +4) -> vectorized V add + store
    const float* vb = vin + (size_t)bh * SEQ * DIM;
    float* ob = outp + (size_t)bh * SEQ * DIM;
#pragma unroll
    for (int et = 0; et < 8; ++et) {
        const size_t idx = (size_t)s * DIM + et * 16 + g * 4;
        f32x4 vv = *(const f32x4*)(vb + idx);
        f32x4 o = acc[et] + vv;
        *(f32x4*)(ob + idx) = o;
    }
}

// ---------------------------------------------------------------------------
// Workspace layout (CH-independent offsets):
//   ws2 = d_ws + 0                      (1 MiB reduced kv, swizzled)
//   ws1 = d_ws + 1 MiB                  (CH * 1 MiB bf16 partials)
// CH=32 needs 33 MiB total; fall back to the proven CH=16 (17 MiB) if the
// harness workspace is smaller.
// ---------------------------------------------------------------------------
extern "C" void kernel_launch(void* const* d_in, const int* in_sizes, int n_in,
                              void* d_out, int out_size, void* d_ws, size_t ws_size,
                              hipStream_t stream) {
    const float* q = (const float*)d_in[0];
    const float* k = (const float*)d_in[1];
    const float* v = (const float*)d_in[2];
    float* out = (float*)d_out;

    __bf16* ws2 = (__bf16*)d_ws;                                   // 1 MiB
    __bf16* ws1 = (__bf16*)d_ws + (size_t)BHN * DIM * DIM;         // partials

    const size_t slab = (size_t)BHN * DIM * DIM * sizeof(__bf16);  // 1 MiB
    if (ws_size >= slab * (1 + 32)) {
        p1_kv<32><<<BHN * 32, 512, 0, stream>>>(k, v, ws1);
        p1_reduce<32><<<256, 256, 0, stream>>>(ws1, ws2);
    } else {
        p1_kv<16><<<BHN * 16, 512, 0, stream>>>(k, v, ws1);
        p1_reduce<16><<<256, 256, 0, stream>>>(ws1, ws2);
    }
    p2_qkv<<<BHN * (SEQ / 128), 512, 0, stream>>>(q, v, ws2, out);
}

// Round 2
// 77.765 us; speedup vs baseline: 1.1040x; 1.1040x over previous
//
#include <hip/hip_runtime.h>
#include <hip/hip_bf16.h>

#define BHN 32      // B*H
#define SEQ 4096
#define DIM 128
#define TROWS 64               // rows per LDS tile

typedef __bf16 bf16x8 __attribute__((ext_vector_type(8)));
typedef __bf16 bf16x4 __attribute__((ext_vector_type(4)));
typedef float  f32x4  __attribute__((ext_vector_type(4)));

__device__ __forceinline__ bf16x8 cvt8(const float* f) {
    bf16x8 r;
#pragma unroll
    for (int i = 0; i < 8; ++i) r[i] = (__bf16)f[i];
    return r;
}

// ---------------------------------------------------------------------------
// Phase 1 (8-wave): partial kv^T. C[e][d] = sum_s v[s][e]*k[s][d]
// CH=32: grid = 32 heads * 32 chunks = 1024 blocks.
// R1 LESSON: __launch_bounds__(512,8) capped unified VGPR+AGPR at 64/lane ->
// allocator spilled the kr/vr staging regs to scratch (VGPR_Count 52->32,
// warm FETCH 16MB->77MB of scratch traffic, dur 48->66us). Occupancy DID
// double (35.8->66.5%) -- the lever works, the spills drowned it.
// NOW: no min-waves clamp. Natural ~52 VGPR + 32 AGPR ~= 84 regs -> 6
// waves/SIMD -> 3 blocks/CU (24 waves/CU, 75% cap), ZERO spills.
// LDS 32 KB (kt/vt [128][64] bf16) -> 5 blocks/CU capacity, reg-limited 3.
// LDS swizzle: elem (d,s) at d*64 + (((s>>3) ^ key(d))*8) + (s&7),
//   key(d) = (d&7) ^ ((d>>2)&7)   -- bijective mod 8 BOTH on consecutive d
//   (read lanes span c) and on stride-4 d (write lanes span dcol) -> <=2-way.
// Staging: per instr a wave reads 2 x 512 B full rows (perfect coalescing).
// ---------------------------------------------------------------------------
template<int CH>
__global__ __launch_bounds__(512) void p1_kv(const float* __restrict__ kin,
                                             const float* __restrict__ vin,
                                             __bf16* __restrict__ ws1) {
    constexpr int SR = SEQ / CH;       // rows per block
    constexpr int NT = SR / TROWS;     // LDS tiles per block

    __shared__ __align__(16) __bf16 kt[DIM][TROWS];  // 16 KB
    __shared__ __align__(16) __bf16 vt[DIM][TROWS];  // 16 KB

    const int bh    = blockIdx.x / CH;
    const int chunk = blockIdx.x % CH;
    const int tid = threadIdx.x;

    const int dcol = tid & 31;     // d-quad index 0..31  -> d0 = dcol*4
    const int sgrp = tid >> 5;     // s-quad index 0..15  -> s0 = sgrp*4
    const int d0 = dcol * 4;
    const int s0 = sgrp * 4;

    const int w = tid >> 6;
    const int l = tid & 63;
    const int g = l >> 4;
    const int c = l & 15;

    const float* kb = kin + (size_t)bh * SEQ * DIM + (size_t)chunk * SR * DIM;
    const float* vb = vin + (size_t)bh * SEQ * DIM + (size_t)chunk * SR * DIM;

    f32x4 acc[8];
#pragma unroll
    for (int nt = 0; nt < 8; ++nt) acc[nt] = (f32x4){0.f, 0.f, 0.f, 0.f};

    for (int t = 0; t < NT; ++t) {
        // ---- load 4 rows x 16B-of-d per thread (wave: 2 full 512B rows/instr)
        const float* kp = kb + (size_t)(t * TROWS + s0) * DIM + d0;
        const float* vp = vb + (size_t)(t * TROWS + s0) * DIM + d0;
        f32x4 kr[4], vr[4];
#pragma unroll
        for (int j = 0; j < 4; ++j) {
            kr[j] = *(const f32x4*)(kp + j * DIM);
            vr[j] = *(const f32x4*)(vp + j * DIM);
        }
        // ---- transpose-pack into swizzled LDS (bf16x4 of 4 s per d-row)
#pragma unroll
        for (int jd = 0; jd < 4; ++jd) {
            const int dd  = d0 + jd;
            const int key = (dd & 7) ^ ((dd >> 2) & 7);
            const int off = (((sgrp >> 1) ^ key) * 8) + (sgrp & 1) * 4;
            bf16x4 pk, pv;
#pragma unroll
            for (int j = 0; j < 4; ++j) {
                pk[j] = (__bf16)kr[j][jd];
                pv[j] = (__bf16)vr[j][jd];
            }
            *(bf16x4*)&kt[dd][off] = pk;
            *(bf16x4*)&vt[dd][off] = pv;
        }
        __syncthreads();

        // ---- MFMA: wave w owns e-strip [w*16, w*16+16); K-dim 64 s (2 steps)
        const int e    = w * 16 + c;
        const int keyE = (e & 7) ^ ((e >> 2) & 7);
#pragma unroll
        for (int st = 0; st < 2; ++st) {
            bf16x8 af = *(const bf16x8*)&vt[e][((st * 4 + g) ^ keyE) * 8];
#pragma unroll
            for (int nt = 0; nt < 8; ++nt) {
                const int d    = nt * 16 + c;
                const int keyD = (d & 7) ^ ((d >> 2) & 7);
                bf16x8 bfr = *(const bf16x8*)&kt[d][((st * 4 + g) ^ keyD) * 8];
                acc[nt] = __builtin_amdgcn_mfma_f32_16x16x32_bf16(af, bfr, acc[nt], 0, 0, 0);
            }
        }
        __syncthreads();
    }

    // store bf16 partials, MFMA-native flat layout: f = nt*2048 + tid*4 + r
    // (each bf16x4 store instr = 512B/wave contiguous burst)
    __bf16* outp = ws1 + ((size_t)chunk * BHN + bh) * (DIM * DIM);
#pragma unroll
    for (int nt = 0; nt < 8; ++nt) {
        bf16x4 p;
#pragma unroll
        for (int r = 0; r < 4; ++r) p[r] = (__bf16)acc[nt][r];
        *(bf16x4*)(outp + nt * 2048 + tid * 4) = p;
    }
}

// ---------------------------------------------------------------------------
// Phase 1.5: reduce CH bf16 partials (fp32 accum) -> bf16 kv^T swizzled for p2:
//   element (e,d) at  e*128 + ((d>>3)^(e&15))*8 + (d&7)
// Decode of p1's flat layout  f = nt*2048 + tid*4 + r, tid = w*64+g*16+c:
//   nt=f>>11; w=(f>>8)&7; g=(f>>6)&3; c=(f>>2)&15; r=f&3
//   e = w*16 + g*4 + r ;  d = nt*16 + c
// 256 blocks * 256 threads; thread owns 8 consecutive f (16B loads/chunk).
// ---------------------------------------------------------------------------
template<int CH>
__global__ __launch_bounds__(256) void p1_reduce(const __bf16* __restrict__ ws1,
                                                 __bf16* __restrict__ ws2) {
    const int t   = blockIdx.x * 256 + threadIdx.x;  // 65536 threads
    const int bh  = t >> 11;
    const int r11 = t & 2047;

    const __bf16* base = ws1 + (size_t)bh * (DIM * DIM) + r11 * 8;
    float s[8] = {0.f, 0.f, 0.f, 0.f, 0.f, 0.f, 0.f, 0.f};
#pragma unroll
    for (int ch = 0; ch < CH; ++ch) {
        bf16x8 a = *(const bf16x8*)(base + (size_t)ch * BHN * DIM * DIM);
#pragma unroll
        for (int i = 0; i < 8; ++i) s[i] += (float)a[i];
    }

    __bf16* dst = ws2 + (size_t)bh * (DIM * DIM);
#pragma unroll
    for (int i = 0; i < 8; ++i) {
        const int f  = r11 * 8 + i;
        const int nt = f >> 11;
        const int wv = (f >> 8) & 7;
        const int gg = (f >> 6) & 3;
        const int cc = (f >> 2) & 15;
        const int r  = f & 3;
        const int e  = wv * 16 + gg * 4 + r;
        const int d  = nt * 16 + cc;
        dst[e * DIM + (((d >> 3) ^ (e & 15)) * 8) + (d & 7)] = (__bf16)s[i];
    }
}

// ---------------------------------------------------------------------------
// Phase 2 (flipped operands): out[s][e] = v[s][e] + sum_d q[s][d] * kv[d][e]
// Compute C[e][s] = mfma(A = kv_frag (M=e), B = q_frag (N=s)).
// Each lane holds 4 CONSECUTIVE e per fragment -> f32x4 epilogue.
// grid = 32 heads * 32 row-chunks = 1024 blocks, 512 threads (8 waves).
// UNCHANGED: VGPR=32 -> 32 waves/CU (grid-limited 4 blocks/CU);
// counters suggest it is near its streaming floor. Attack next if p1 pays off.
// ---------------------------------------------------------------------------
__global__ __launch_bounds__(512) void p2_qkv(const float* __restrict__ qin,
                                              const float* __restrict__ vin,
                                              const __bf16* __restrict__ ws2,
                                              float* __restrict__ outp) {
    __shared__ __align__(16) __bf16 kvs[DIM * DIM];

    const int bh = blockIdx.x & 31;
    const int rc = blockIdx.x >> 5;
    const int tid = threadIdx.x;

    {   // linear 16B-copy of the (already swizzled) 32 KB head slab into LDS
        const uint4* src = (const uint4*)(ws2 + (size_t)bh * DIM * DIM);
        uint4* dst = (uint4*)kvs;
#pragma unroll
        for (int j = 0; j < 4; ++j) dst[tid + j * 512] = src[tid + j * 512];
    }
    __syncthreads();

    const int w = tid >> 6;
    const int l = tid & 63;
    const int g = l >> 4;
    const int c = l & 15;
    const int s = rc * 128 + w * 16 + c;     // this lane's output row

    // hoist all 4 Q fragments: B[d][s], lane holds q[s][ks*32 + g*8 .. +8)
    const float* qrow = qin + (size_t)bh * SEQ * DIM + (size_t)s * DIM + g * 8;
    bf16x8 bq[4];
#pragma unroll
    for (int ks = 0; ks < 4; ++ks) {
        f32x4 x = *(const f32x4*)(qrow + ks * 32);
        f32x4 y = *(const f32x4*)(qrow + ks * 32 + 4);
        float tmp[8];
        tmp[0]=x[0]; tmp[1]=x[1]; tmp[2]=x[2]; tmp[3]=x[3];
        tmp[4]=y[0]; tmp[5]=y[1]; tmp[6]=y[2]; tmp[7]=y[3];
        bq[ks] = cvt8(tmp);
    }

    f32x4 acc[8];
#pragma unroll
    for (int et = 0; et < 8; ++et) acc[et] = (f32x4){0.f, 0.f, 0.f, 0.f};

#pragma unroll
    for (int ks = 0; ks < 4; ++ks) {
#pragma unroll
        for (int et = 0; et < 8; ++et) {
            const int e = et * 16 + c;                 // A's M index = lane&15
            const int slot = (ks * 4 + g) ^ c;         // unswizzle: d-slice = ks*32+g*8
            bf16x8 a = *(const bf16x8*)&kvs[e * DIM + slot * 8];
            acc[et] = __builtin_amdgcn_mfma_f32_16x16x32_bf16(a, bq[ks], acc[et], 0, 0, 0);
        }
    }

    // epilogue: lane holds out[s][et*16 + g*4 .. +4) -> vectorized V add + store
    const float* vb = vin + (size_t)bh * SEQ * DIM;
    float* ob = outp + (size_t)bh * SEQ * DIM;
#pragma unroll
    for (int et = 0; et < 8; ++et) {
        const size_t idx = (size_t)s * DIM + et * 16 + g * 4;
        f32x4 vv = *(const f32x4*)(vb + idx);
        f32x4 o = acc[et] + vv;
        *(f32x4*)(ob + idx) = o;
    }
}

// ---------------------------------------------------------------------------
// Workspace layout (CH-independent offsets):
//   ws2 = d_ws + 0                      (1 MiB reduced kv, swizzled)
//   ws1 = d_ws + 1 MiB                  (CH * 1 MiB bf16 partials)
// CH=32 needs 33 MiB total; fall back to the proven CH=16 (17 MiB) if the
// harness workspace is smaller.
// ---------------------------------------------------------------------------
extern "C" void kernel_launch(void* const* d_in, const int* in_sizes, int n_in,
                              void* d_out, int out_size, void* d_ws, size_t ws_size,
                              hipStream_t stream) {
    const float* q = (const float*)d_in[0];
    const float* k = (const float*)d_in[1];
    const float* v = (const float*)d_in[2];
    float* out = (float*)d_out;

    __bf16* ws2 = (__bf16*)d_ws;                                   // 1 MiB
    __bf16* ws1 = (__bf16*)d_ws + (size_t)BHN * DIM * DIM;         // partials

    const size_t slab = (size_t)BHN * DIM * DIM * sizeof(__bf16);  // 1 MiB
    if (ws_size >= slab * (1 + 32)) {
        p1_kv<32><<<BHN * 32, 512, 0, stream>>>(k, v, ws1);
        p1_reduce<32><<<256, 256, 0, stream>>>(ws1, ws2);
    } else {
        p1_kv<16><<<BHN * 16, 512, 0, stream>>>(k, v, ws1);
        p1_reduce<16><<<256, 256, 0, stream>>>(ws1, ws2);
    }
    p2_qkv<<<BHN * (SEQ / 128), 512, 0, stream>>>(q, v, ws2, out);
}

// Round 3
// 68.405 us; speedup vs baseline: 1.2551x; 1.1368x over previous
//
#include <hip/hip_runtime.h>
#include <hip/hip_bf16.h>

#define BHN 32      // B*H
#define SEQ 4096
#define DIM 128
#define TROWS 64               // rows per LDS tile

typedef __bf16 bf16x8 __attribute__((ext_vector_type(8)));
typedef __bf16 bf16x4 __attribute__((ext_vector_type(4)));
typedef float  f32x4  __attribute__((ext_vector_type(4)));

__device__ __forceinline__ bf16x8 cvt8(const float* f) {
    bf16x8 r;
#pragma unroll
    for (int i = 0; i < 8; ++i) r[i] = (__bf16)f[i];
    return r;
}

__device__ __forceinline__ void load8(const float* kp, const float* vp,
                                      f32x4 kr[4], f32x4 vr[4]) {
#pragma unroll
    for (int j = 0; j < 4; ++j) {
        kr[j] = *(const f32x4*)(kp + j * DIM);
        vr[j] = *(const f32x4*)(vp + j * DIM);
    }
}

// ---------------------------------------------------------------------------
// Phase 1 (8-wave): partial kv^T. C[e][d] = sum_s v[s][e]*k[s][d]
// CH=16 (R2 lesson: CH=32 doubled partial traffic for zero occupancy gain --
// occupancy is register-capped at ~2 blocks/CU regardless of grid).
//
// R3 changes, attacking the measured ~2.7 TB/s effective read service while
// every pipe idles (MfmaUtil 2.6%, VALU 3.3%, HBM 22%):
//  (1) INTERLEAVED tile mapping: chunk c processes row-tiles {c, c+CH, ...}
//      instead of a contiguous 256-KB slab. Kills the 2^18-byte base stride
//      across 512 phase-locked blocks (HBM channel camping); at any instant
//      a head's 16 chunks read one contiguous moving window -> all channels.
//      Chunk partial = sum over a different s-subset; reduce unchanged.
//  (2) REGISTER DOUBLE-BUFFER prefetch: issue tile t+1's 8 loads before
//      pack(t)/MFMA(t). kr/vr[2][4], statically indexed after full unroll
//      (rule: runtime-indexed ext_vector arrays -> scratch). ~112 regs
//      (<=128) -> occupancy unchanged; loads now have a full phase in
//      flight before their pack consumes them.
//
// LDS swizzle unchanged: elem (d,s) at d*64 + (((s>>3) ^ key(d))*8) + (s&7),
//   key(d) = (d&7) ^ ((d>>2)&7)  -> <=2-way on both write and read lanes.
// ---------------------------------------------------------------------------
template<int CH>
__global__ __launch_bounds__(512) void p1_kv(const float* __restrict__ kin,
                                             const float* __restrict__ vin,
                                             __bf16* __restrict__ ws1) {
    constexpr int SR = SEQ / CH;       // rows per block
    constexpr int NT = SR / TROWS;     // tiles per block (4 at CH=16)

    __shared__ __align__(16) __bf16 kt[DIM][TROWS];  // 16 KB
    __shared__ __align__(16) __bf16 vt[DIM][TROWS];  // 16 KB

    const int bh    = blockIdx.x / CH;
    const int chunk = blockIdx.x % CH;
    const int tid = threadIdx.x;

    const int dcol = tid & 31;     // d-quad index 0..31  -> d0 = dcol*4
    const int sgrp = tid >> 5;     // s-quad index 0..15  -> s0 = sgrp*4
    const int d0 = dcol * 4;
    const int s0 = sgrp * 4;

    const int w = tid >> 6;
    const int l = tid & 63;
    const int g = l >> 4;
    const int c = l & 15;

    const float* hk = kin + (size_t)bh * SEQ * DIM;
    const float* hv = vin + (size_t)bh * SEQ * DIM;

    f32x4 acc[8];
#pragma unroll
    for (int nt = 0; nt < 8; ++nt) acc[nt] = (f32x4){0.f, 0.f, 0.f, 0.f};

    // ping-pong staging buffers; all indices compile-time after full unroll
    f32x4 kr[2][4], vr[2][4];
    {   // prologue: tile 0 of this chunk = global row-tile 'chunk'
        const size_t off = ((size_t)chunk * TROWS + s0) * DIM + d0;
        load8(hk + off, hv + off, kr[0], vr[0]);
    }

#pragma unroll
    for (int t = 0; t < NT; ++t) {
        const int cur = t & 1;

        // ---- prefetch next tile (global row-tile (t+1)*CH + chunk) first,
        //      so its 8 loads are in flight across pack+barriers+MFMA
        if (t + 1 < NT) {
            const size_t off =
                ((size_t)((t + 1) * CH + chunk) * TROWS + s0) * DIM + d0;
            load8(hk + off, hv + off, kr[cur ^ 1], vr[cur ^ 1]);
        }

        // ---- transpose-pack current tile into swizzled LDS
#pragma unroll
        for (int jd = 0; jd < 4; ++jd) {
            const int dd  = d0 + jd;
            const int key = (dd & 7) ^ ((dd >> 2) & 7);
            const int off = (((sgrp >> 1) ^ key) * 8) + (sgrp & 1) * 4;
            bf16x4 pk, pv;
#pragma unroll
            for (int j = 0; j < 4; ++j) {
                pk[j] = (__bf16)kr[cur][j][jd];
                pv[j] = (__bf16)vr[cur][j][jd];
            }
            *(bf16x4*)&kt[dd][off] = pk;
            *(bf16x4*)&vt[dd][off] = pv;
        }
        __syncthreads();

        // ---- MFMA: wave w owns e-strip [w*16, w*16+16); K-dim 64 s (2 steps)
        const int e    = w * 16 + c;
        const int keyE = (e & 7) ^ ((e >> 2) & 7);
#pragma unroll
        for (int st = 0; st < 2; ++st) {
            bf16x8 af = *(const bf16x8*)&vt[e][((st * 4 + g) ^ keyE) * 8];
#pragma unroll
            for (int nt = 0; nt < 8; ++nt) {
                const int d    = nt * 16 + c;
                const int keyD = (d & 7) ^ ((d >> 2) & 7);
                bf16x8 bfr = *(const bf16x8*)&kt[d][((st * 4 + g) ^ keyD) * 8];
                acc[nt] = __builtin_amdgcn_mfma_f32_16x16x32_bf16(af, bfr, acc[nt], 0, 0, 0);
            }
        }
        __syncthreads();
    }

    // store bf16 partials, MFMA-native flat layout: f = nt*2048 + tid*4 + r
    // (each bf16x4 store instr = 512B/wave contiguous burst)
    __bf16* outp = ws1 + ((size_t)chunk * BHN + bh) * (DIM * DIM);
#pragma unroll
    for (int nt = 0; nt < 8; ++nt) {
        bf16x4 p;
#pragma unroll
        for (int r = 0; r < 4; ++r) p[r] = (__bf16)acc[nt][r];
        *(bf16x4*)(outp + nt * 2048 + tid * 4) = p;
    }
}

// ---------------------------------------------------------------------------
// Phase 1.5: reduce CH bf16 partials (fp32 accum) -> bf16 kv^T swizzled for p2:
//   element (e,d) at  e*128 + ((d>>3)^(e&15))*8 + (d&7)
// Decode of p1's flat layout  f = nt*2048 + tid*4 + r, tid = w*64+g*16+c:
//   nt=f>>11; w=(f>>8)&7; g=(f>>6)&3; c=(f>>2)&15; r=f&3
//   e = w*16 + g*4 + r ;  d = nt*16 + c
// 256 blocks * 256 threads; thread owns 8 consecutive f (16B loads/chunk).
// ---------------------------------------------------------------------------
template<int CH>
__global__ __launch_bounds__(256) void p1_reduce(const __bf16* __restrict__ ws1,
                                                 __bf16* __restrict__ ws2) {
    const int t   = blockIdx.x * 256 + threadIdx.x;  // 65536 threads
    const int bh  = t >> 11;
    const int r11 = t & 2047;

    const __bf16* base = ws1 + (size_t)bh * (DIM * DIM) + r11 * 8;
    float s[8] = {0.f, 0.f, 0.f, 0.f, 0.f, 0.f, 0.f, 0.f};
#pragma unroll
    for (int ch = 0; ch < CH; ++ch) {
        bf16x8 a = *(const bf16x8*)(base + (size_t)ch * BHN * DIM * DIM);
#pragma unroll
        for (int i = 0; i < 8; ++i) s[i] += (float)a[i];
    }

    __bf16* dst = ws2 + (size_t)bh * (DIM * DIM);
#pragma unroll
    for (int i = 0; i < 8; ++i) {
        const int f  = r11 * 8 + i;
        const int nt = f >> 11;
        const int wv = (f >> 8) & 7;
        const int gg = (f >> 6) & 3;
        const int cc = (f >> 2) & 15;
        const int r  = f & 3;
        const int e  = wv * 16 + gg * 4 + r;
        const int d  = nt * 16 + cc;
        dst[e * DIM + (((d >> 3) ^ (e & 15)) * 8) + (d & 7)] = (__bf16)s[i];
    }
}

// ---------------------------------------------------------------------------
// Phase 2 (flipped operands): out[s][e] = v[s][e] + sum_d q[s][d] * kv[d][e]
// Compute C[e][s] = mfma(A = kv_frag (M=e), B = q_frag (N=s)).
// Each lane holds 4 CONSECUTIVE e per fragment -> f32x4 epilogue.
// grid = 32 heads * 32 row-chunks = 1024 blocks, 512 threads (8 waves).
// UNCHANGED: VGPR=32 -> 32 waves/CU; near its streaming floor per counters.
// ---------------------------------------------------------------------------
__global__ __launch_bounds__(512) void p2_qkv(const float* __restrict__ qin,
                                              const float* __restrict__ vin,
                                              const __bf16* __restrict__ ws2,
                                              float* __restrict__ outp) {
    __shared__ __align__(16) __bf16 kvs[DIM * DIM];

    const int bh = blockIdx.x & 31;
    const int rc = blockIdx.x >> 5;
    const int tid = threadIdx.x;

    {   // linear 16B-copy of the (already swizzled) 32 KB head slab into LDS
        const uint4* src = (const uint4*)(ws2 + (size_t)bh * DIM * DIM);
        uint4* dst = (uint4*)kvs;
#pragma unroll
        for (int j = 0; j < 4; ++j) dst[tid + j * 512] = src[tid + j * 512];
    }
    __syncthreads();

    const int w = tid >> 6;
    const int l = tid & 63;
    const int g = l >> 4;
    const int c = l & 15;
    const int s = rc * 128 + w * 16 + c;     // this lane's output row

    // hoist all 4 Q fragments: B[d][s], lane holds q[s][ks*32 + g*8 .. +8)
    const float* qrow = qin + (size_t)bh * SEQ * DIM + (size_t)s * DIM + g * 8;
    bf16x8 bq[4];
#pragma unroll
    for (int ks = 0; ks < 4; ++ks) {
        f32x4 x = *(const f32x4*)(qrow + ks * 32);
        f32x4 y = *(const f32x4*)(qrow + ks * 32 + 4);
        float tmp[8];
        tmp[0]=x[0]; tmp[1]=x[1]; tmp[2]=x[2]; tmp[3]=x[3];
        tmp[4]=y[0]; tmp[5]=y[1]; tmp[6]=y[2]; tmp[7]=y[3];
        bq[ks] = cvt8(tmp);
    }

    f32x4 acc[8];
#pragma unroll
    for (int et = 0; et < 8; ++et) acc[et] = (f32x4){0.f, 0.f, 0.f, 0.f};

#pragma unroll
    for (int ks = 0; ks < 4; ++ks) {
#pragma unroll
        for (int et = 0; et < 8; ++et) {
            const int e = et * 16 + c;                 // A's M index = lane&15
            const int slot = (ks * 4 + g) ^ c;         // unswizzle: d-slice = ks*32+g*8
            bf16x8 a = *(const bf16x8*)&kvs[e * DIM + slot * 8];
            acc[et] = __builtin_amdgcn_mfma_f32_16x16x32_bf16(a, bq[ks], acc[et], 0, 0, 0);
        }
    }

    // epilogue: lane holds out[s][et*16 + g*4 .. +4) -> vectorized V add + store
    const float* vb = vin + (size_t)bh * SEQ * DIM;
    float* ob = outp + (size_t)bh * SEQ * DIM;
#pragma unroll
    for (int et = 0; et < 8; ++et) {
        const size_t idx = (size_t)s * DIM + et * 16 + g * 4;
        f32x4 vv = *(const f32x4*)(vb + idx);
        f32x4 o = acc[et] + vv;
        *(f32x4*)(ob + idx) = o;
    }
}

// ---------------------------------------------------------------------------
// Workspace: ws2 (1 MiB reduced kv) + ws1 (16 x 1 MiB bf16 partials) = 17 MiB.
// ---------------------------------------------------------------------------
extern "C" void kernel_launch(void* const* d_in, const int* in_sizes, int n_in,
                              void* d_out, int out_size, void* d_ws, size_t ws_size,
                              hipStream_t stream) {
    const float* q = (const float*)d_in[0];
    const float* k = (const float*)d_in[1];
    const float* v = (const float*)d_in[2];
    float* out = (float*)d_out;

    __bf16* ws2 = (__bf16*)d_ws;                                   // 1 MiB
    __bf16* ws1 = (__bf16*)d_ws + (size_t)BHN * DIM * DIM;         // partials

    p1_kv<16><<<BHN * 16, 512, 0, stream>>>(k, v, ws1);
    p1_reduce<16><<<256, 256, 0, stream>>>(ws1, ws2);
    p2_qkv<<<BHN * (SEQ / 128), 512, 0, stream>>>(q, v, ws2, out);
}